// Round 11
// baseline (759.370 us; speedup 1.0000x reference)
//
#include <hip/hip_runtime.h>

#define SEQ   512
#define NTHR  256
#define NBLK  256

typedef _Float16 f16x8 __attribute__((ext_vector_type(8)));
typedef float    f32x4 __attribute__((ext_vector_type(4)));

#define MFMA(a, b, c) __builtin_amdgcn_mfma_f32_16x16x32_f16((a), (b), (c), 0, 0, 0)

__device__ __forceinline__ float sig_(float x) {
    return __builtin_amdgcn_rcpf(1.0f + __builtin_amdgcn_exp2f(x * -1.4426950408889634f));
}
// sign-safe tanh via 2*sigmoid(2x)-1
__device__ __forceinline__ float tanh_(float x) {
    return fmaf(2.0f, __builtin_amdgcn_rcpf(1.0f + __builtin_amdgcn_exp2f(x * -2.8853900817779268f)), -1.0f);
}

// One wave per layer (4 waves/block). Wave ell owns ALL 16 M-tiles of its layer,
// so the self-recurrence h_ell(t-1) -> h_ell(t) is IN-WAVE (no barrier). Layers
// are skewed 2 ticks (layer ell processes t = tau - 2*ell), making the
// cross-layer dependency 2 ticks old -> ONE __syncthreads per 2 ticks.
// h ring: write slot tau&3, self-read (tau-1)&3, in-read (tau-2)&3.
// Quad-replica gate trick: quad member k=bc>>2 owns tiles {k,k+4,k+8,k+12};
// its acc[0..3] are gates i,f,g,o of (m=(g*4+k)*4+lam, b=bc&3) -> in-lane gates.
__global__ __launch_bounds__(NTHR, 1) void lstm4_deep(
    const float* __restrict__ x,
    const float* __restrict__ W0, const float* __restrict__ B0,
    const float* __restrict__ W1, const float* __restrict__ B1,
    const float* __restrict__ W2, const float* __restrict__ B2,
    const float* __restrict__ W3, const float* __restrict__ B3,
    const float* __restrict__ ln_g, const float* __restrict__ ln_b,
    const float* __restrict__ Wout, const float* __restrict__ bout,
    float* __restrict__ out)
{
    __shared__ __align__(16) _Float16 hbuf[4][4][4][64];   // [slot][layer][b][k]  8 KB
    __shared__ float xall[4][SEQ];                         // 8 KB
    __shared__ float sconst[2];

    const int tid  = threadIdx.x;
    const int lane = tid & 63;
    const int ell  = tid >> 6;        // wave == layer
    const int lam  = lane >> 4;
    const int bc   = lane & 15;
    const int br   = bc & 3;
    const int kq   = bc >> 2;
    const int bb   = blockIdx.x;

    // ---- stage x, zero h (all 4 slots) ----
    for (int i = tid; i < 4 * SEQ; i += NTHR)
        xall[i >> 9][i & 511] = x[bb * 4 * SEQ + i];
    for (int i = tid; i < 4 * 4 * 4 * 64; i += NTHR)
        ((_Float16*)hbuf)[i] = (_Float16)0.0f;

    if (tid < 64) {
        float a = ln_g[tid] * Wout[tid];
        float b = ln_b[tid] * Wout[tid];
#pragma unroll
        for (int off = 32; off > 0; off >>= 1) {
            a += __shfl_xor(a, off, 64);
            b += __shfl_xor(b, off, 64);
        }
        if (tid == 0) { sconst[0] = a; sconst[1] = b; }
    }

    const float* Wp = (ell == 0) ? W0 : (ell == 1) ? W1 : (ell == 2) ? W2 : W3;
    const float* Bp = (ell == 0) ? B0 : (ell == 1) ? B1 : (ell == 2) ? B2 : B3;

    // ---- whole layer's weights in registers: 16 tiles x 4 frags (f16) ----
    f16x8 wf[16][4];
    f32x4 biasv[16];
#pragma unroll
    for (int T = 0; T < 16; ++T) {
        const int cA = (bc & 3) * 64 + T * 4 + (bc >> 2);   // gate-permuted col
        if (ell == 0) {
#pragma unroll
            for (int kt = 0; kt < 2; ++kt)
#pragma unroll
                for (int e = 0; e < 8; ++e)
                    wf[T][kt][e] = (_Float16)W0[(1 + kt * 32 + lam * 8 + e) * 256 + cA];
#pragma unroll
            for (int e = 0; e < 8; ++e) { wf[T][2][e] = (_Float16)0.0f; wf[T][3][e] = (_Float16)0.0f; }
            if (lam == 0) wf[T][2][0] = (_Float16)W0[cA];   // x weight, one-hot A-frag
        } else {
#pragma unroll
            for (int kt = 0; kt < 4; ++kt)        // kt 0..1 = in-h, 2..3 = self-h
#pragma unroll
                for (int e = 0; e < 8; ++e)
                    wf[T][kt][e] = (_Float16)Wp[(kt * 32 + lam * 8 + e) * 256 + cA];
        }
#pragma unroll
        for (int r = 0; r < 4; ++r)
            biasv[T][r] = Bp[r * 64 + T * 4 + lam];
    }

    // owned-tile (per group) constants
    float gwv[4];
    int   wrg[4];
#pragma unroll
    for (int g = 0; g < 4; ++g) {
        const int m = (g * 4 + kq) * 4 + lam;
        gwv[g] = ln_g[m] * Wout[m];
        wrg[g] = br * 128 + (((m >> 3) ^ br) * 16) + (m & 7) * 2;   // chunk-XOR swizzle
    }

    // B-frag read offsets within one [4][64] f16 layer buffer (pad lanes broadcast br)
    const int a0 = br * 128 + ((lam)     ^ br) * 16;
    const int a1 = br * 128 + ((4 + lam) ^ br) * 16;
    const bool k1b = (bc & 4) != 0;
    const bool k2b = (bc & 8) != 0;

    float cst[4] = {0.f, 0.f, 0.f, 0.f};
    char* const hb = (char*)hbuf;

    __syncthreads();
    const float Sgw = sconst[0];
    const float Sbw = sconst[1] + bout[0];

    for (int tau = 0; tau < SEQ + 6; ++tau) {
        const int t = tau - 2 * ell;
        if (t >= 0 && t < SEQ) {
            const char* selfB = hb + ((((tau - 1) & 3) * 4 + ell) * 512);
            f16x8 b0, b1, b2, b3;
            if (ell == 0) {
                b0 = *(const f16x8*)(selfB + a0);
                b1 = *(const f16x8*)(selfB + a1);
                f16x8 xf;
#pragma unroll
                for (int e = 0; e < 8; ++e) xf[e] = (_Float16)0.0f;
                if (lam == 0) xf[0] = (_Float16)xall[br][t];   // one-hot x B-frag
                b2 = xf; b3 = xf;
            } else {
                const char* inB = hb + ((((tau - 2) & 3) * 4 + (ell - 1)) * 512);
                b0 = *(const f16x8*)(inB + a0);
                b1 = *(const f16x8*)(inB + a1);
                b2 = *(const f16x8*)(selfB + a0);
                b3 = *(const f16x8*)(selfB + a1);
            }

            char* hw = hb + (((tau & 3) * 4 + ell) * 512);
            float s1 = 0.0f, s2 = 0.0f, s3 = 0.0f;

#pragma unroll
            for (int g = 0; g < 4; ++g) {
                f32x4 A0 = MFMA(wf[4 * g + 0][0], b0, biasv[4 * g + 0]);
                f32x4 A1 = MFMA(wf[4 * g + 1][0], b0, biasv[4 * g + 1]);
                f32x4 A2 = MFMA(wf[4 * g + 2][0], b0, biasv[4 * g + 2]);
                f32x4 A3 = MFMA(wf[4 * g + 3][0], b0, biasv[4 * g + 3]);
                A0 = MFMA(wf[4 * g + 0][1], b1, A0);
                A1 = MFMA(wf[4 * g + 1][1], b1, A1);
                A2 = MFMA(wf[4 * g + 2][1], b1, A2);
                A3 = MFMA(wf[4 * g + 3][1], b1, A3);
                A0 = MFMA(wf[4 * g + 0][2], b2, A0);
                A1 = MFMA(wf[4 * g + 1][2], b2, A1);
                A2 = MFMA(wf[4 * g + 2][2], b2, A2);
                A3 = MFMA(wf[4 * g + 3][2], b2, A3);
                if (ell != 0) {
                    A0 = MFMA(wf[4 * g + 0][3], b3, A0);
                    A1 = MFMA(wf[4 * g + 1][3], b3, A1);
                    A2 = MFMA(wf[4 * g + 2][3], b3, A2);
                    A3 = MFMA(wf[4 * g + 3][3], b3, A3);
                }
                // select owned tile's acc (quad member kq owns tile 4g+kq)
                const f32x4 s01 = k1b ? A1 : A0;
                const f32x4 s23 = k1b ? A3 : A2;
                const f32x4 aK  = k2b ? s23 : s01;
                // straight-line in-lane gates
                const float gi = sig_(aK[0]);
                const float gf = sig_(aK[1]);
                const float gg = tanh_(aK[2]);
                const float go = sig_(aK[3]);
                cst[g] = fmaf(gf, cst[g], gi * gg);
                const float hn = go * tanh_(cst[g]);
                *(_Float16*)(hw + wrg[g]) = (_Float16)hn;
                if (ell == 3) { s1 += hn; s2 = fmaf(hn, hn, s2); s3 = fmaf(hn, gwv[g], s3); }
            }

            // LN + projection, fully inside the layer-3 wave
            if (ell == 3) {
                s1 += __shfl_xor(s1, 4, 64);  s2 += __shfl_xor(s2, 4, 64);  s3 += __shfl_xor(s3, 4, 64);
                s1 += __shfl_xor(s1, 8, 64);  s2 += __shfl_xor(s2, 8, 64);  s3 += __shfl_xor(s3, 8, 64);
                s1 += __shfl_xor(s1, 16, 64); s2 += __shfl_xor(s2, 16, 64); s3 += __shfl_xor(s3, 16, 64);
                s1 += __shfl_xor(s1, 32, 64); s2 += __shfl_xor(s2, 32, 64); s3 += __shfl_xor(s3, 32, 64);
                if (lane < 4) {
                    const float mu = s1 * (1.0f / 64.0f);
                    float var = fmaf(s2, 1.0f / 64.0f, -mu * mu);
                    var = fmaxf(var, 0.0f);
                    const float rs = rsqrtf(var + 1e-5f);
                    out[(bb * 4 + lane) * SEQ + t] = fmaf(rs, fmaf(-mu, Sgw, s3), Sbw);
                }
            }
        }
        if (tau & 1) __syncthreads();
    }
}

extern "C" void kernel_launch(void* const* d_in, const int* in_sizes, int n_in,
                              void* d_out, int out_size, void* d_ws, size_t ws_size,
                              hipStream_t stream)
{
    const float* x    = (const float*)d_in[0];
    const float* W0   = (const float*)d_in[1];
    const float* B0   = (const float*)d_in[2];
    const float* W1   = (const float*)d_in[3];
    const float* B1   = (const float*)d_in[4];
    const float* W2   = (const float*)d_in[5];
    const float* B2   = (const float*)d_in[6];
    const float* W3   = (const float*)d_in[7];
    const float* B3   = (const float*)d_in[8];
    const float* ln_g = (const float*)d_in[9];
    const float* ln_b = (const float*)d_in[10];
    const float* Wout = (const float*)d_in[11];
    const float* bout = (const float*)d_in[12];
    float* out = (float*)d_out;

    lstm4_deep<<<NBLK, NTHR, 0, stream>>>(x, W0, B0, W1, B1, W2, B2, W3, B3,
                                          ln_g, ln_b, Wout, bout, out);
}